// Round 14
// baseline (81.344 us; speedup 1.0000x reference)
//
#include <hip/hip_runtime.h>

#define NB 16     // batch
#define CD 128    // channels
#define HW 4096   // spatial L
#define DD 512    // projected dim
#define KC 64     // clusters

typedef __attribute__((ext_vector_type(8))) short bfrag;           // 8 bf16 (4 VGPR)
typedef __attribute__((ext_vector_type(4))) float facc;            // MFMA acc

__device__ __forceinline__ unsigned short f2bf(float f) {
  union { float f; unsigned u; } v; v.f = f;
  unsigned r = v.u + 0x7fffu + ((v.u >> 16) & 1u);   // RNE
  return (unsigned short)(r >> 16);
}
__device__ __forceinline__ float bf2f(unsigned short h) {
  union { unsigned u; float f; } v; v.u = ((unsigned)h) << 16; return v.f;
}
// packed f32x2 -> bf16x2 (RNE), low16 = lo
__device__ __forceinline__ unsigned f2bf2(float lo, float hi) {
  unsigned r;
  asm("v_cvt_pk_bf16_f32 %0, %1, %2" : "=v"(r) : "v"(lo), "v"(hi));
  return r;
}
// async global->LDS: HW writes lds_base + lane*16; global src carries per-lane offset
__device__ __forceinline__ void gll16(const void* g, void* l) {
  __builtin_amdgcn_global_load_lds(
      (__attribute__((address_space(1))) void*)(uintptr_t)g,
      (__attribute__((address_space(3))) void*)(uintptr_t)l, 16, 0, 0);
}
// row swizzle: spreads row-parallel accesses across 8 16B slots
__device__ __forceinline__ int swzr(int r) { return ((r & 7) ^ ((r >> 3) & 7)) << 4; }

// ---------- prep: pre-swizzled W images + plain normalized centroids ----------
// Wsw: 4 images x [128d x 256B], byte = dch*32768 + d*256 + ((c*2)^swzr(d))
// Cb:  (K,D) row-major bf16, L2-resident (read direct by k_xproj e-MFMA)
__global__ __launch_bounds__(256) void k_prep(const float* __restrict__ conv_w,
                                              const float* __restrict__ centroids,
                                              unsigned short* __restrict__ Wsw,
                                              unsigned short* __restrict__ Cb) {
  int b = blockIdx.x, t = threadIdx.x;
  if (b < KC) {
    const float* row = centroids + (size_t)b * DD;
    float v0 = row[t], v1 = row[t + 256];
    float ss = v0 * v0 + v1 * v1;
    #pragma unroll
    for (int off = 32; off; off >>= 1) ss += __shfl_xor(ss, off);
    __shared__ float red[4];
    if ((t & 63) == 0) red[t >> 6] = ss;
    __syncthreads();
    float tot = red[0] + red[1] + red[2] + red[3];
    float inv = 1.0f / fmaxf(sqrtf(tot), 1e-12f);
    Cb[(size_t)b * DD + t]       = f2bf(v0 * inv);
    Cb[(size_t)b * DD + t + 256] = f2bf(v1 * inv);
  } else {
    int i = (b - KC) * 2048 + t * 8;            // 32 blocks cover 512x128
    const float4* src = (const float4*)(conv_w + i);
    float4 a = src[0], c4 = src[1];
    int d = i >> 7, c0 = i & 127;
    int dch = d >> 7, dl = d & 127;
    uint4 w;
    w.x = f2bf2(a.x, a.y);   w.y = f2bf2(a.z, a.w);
    w.z = f2bf2(c4.x, c4.y); w.w = f2bf2(c4.z, c4.w);
    *(uint4*)((char*)Wsw + dch * 32768 + dl * 256 + ((c0 * 2) ^ swzr(dl))) = w;
  }
}

// ---------- fused xnorm + projection + logits/exp (R13 structure, 65.5K LDS) ----------
// 2 blocks/CU: LDS = Xraw/fbuf 32K | Ws/etile 32K | invb+ps 1.5K.
// Cb read direct from global (L2-hot); bfh hoisted so Xraw dies pre-loop.
__global__ __launch_bounds__(512, 4) void k_xproj(const float* __restrict__ x,
                                                  const unsigned short* __restrict__ Wsw,
                                                  const unsigned short* __restrict__ Cb,
                                                  const float* __restrict__ conv_b,
                                                  unsigned short* __restrict__ fT,
                                                  unsigned short* __restrict__ eg,
                                                  float* __restrict__ psums) {
  __shared__ __align__(16) char smem[67072];
  char* Xraw = smem;                      // 128l x 256B: l*256 + ((c*2)^swzr(l))
  char* fbuf = smem;                      // aliases Xraw (dead after bfh hoist)
  char* Ws   = smem + 32768;              // 128d x 256B (staged image)
  char* etile = smem + 32768;             // aliases Ws (dead after dch3 f-MFMA)
  float* invb = (float*)(smem + 65536);   // [128]
  float* ps   = (float*)(smem + 66048);   // [64][4]
  int n = blockIdx.y, lblk = blockIdx.x, l0 = lblk * 128;
  int t = threadIdx.x, lane = t & 63, wid = t >> 6;

  // prologue: stage Ws(0)
  #pragma unroll
  for (int q = 0; q < 4; q++)
    gll16((const char*)Wsw + (q * 8 + wid) * 1024 + lane * 16, Ws + (q * 8 + wid) * 1024);

  // P1: x fp32 (c-pair rows) -> bf16 -> Xraw (l,c), u32 pair-writes
  #pragma unroll
  for (int j = 0; j < 2; j++) {
    int c0 = ((t >> 4) + 32 * j) * 2;
    const float4* r0p = (const float4*)(x + ((size_t)n * CD + c0) * HW + l0);
    const float4* r1p = (const float4*)(x + ((size_t)n * CD + c0 + 1) * HW + l0);
    #pragma unroll
    for (int jj = 0; jj < 2; jj++) {
      int f4 = (t & 15) + 16 * jj;
      float4 a = r0p[f4], b = r1p[f4];
      int lb = f4 * 4;
      *(unsigned*)(Xraw + (lb + 0) * 256 + ((c0 * 2) ^ swzr(lb + 0))) = f2bf2(a.x, b.x);
      *(unsigned*)(Xraw + (lb + 1) * 256 + ((c0 * 2) ^ swzr(lb + 1))) = f2bf2(a.y, b.y);
      *(unsigned*)(Xraw + (lb + 2) * 256 + ((c0 * 2) ^ swzr(lb + 2))) = f2bf2(a.z, b.z);
      *(unsigned*)(Xraw + (lb + 3) * 256 + ((c0 * 2) ^ swzr(lb + 3))) = f2bf2(a.w, b.w);
    }
  }
  __syncthreads();                        // B-P1: Xraw ready; Ws(0) drained

  // P2: inv[l] from row sums (b128 reads; XOR permutation is sum-invariant)
  {
    int l = t >> 2;
    float ss = 0.f;
    #pragma unroll
    for (int p = 0; p < 4; p++) {
      int s16 = (t & 3) + 4 * p;
      bfrag v = *(const bfrag*)(Xraw + l * 256 + ((s16 * 16) ^ swzr(l)));
      #pragma unroll
      for (int i = 0; i < 8; i++) { float f = bf2f((unsigned short)v[i]); ss += f * f; }
    }
    ss += __shfl_xor(ss, 1); ss += __shfl_xor(ss, 2);
    if ((t & 3) == 0) invb[l] = 1.0f / fmaxf(sqrtf(ss), 1e-12f);
  }
  __syncthreads();                        // B-P2: invb ready

  int wr = wid >> 1, wc = wid & 1;        // f waves: 4(l-grp of 32) x 2(d-grp of 64)
  int er = wid >> 2, ec = wid & 3;        // e waves: 2(k) x 4(l)
  int r0 = (lane >> 4) << 2, cl = lane & 15;
  int hi8 = (lane >> 4) << 3;

  // hoist Xraw B-fragments (dch-invariant, 32 VGPR) + per-l-frag inv
  bfrag bfh[4][2];
  #pragma unroll
  for (int kk = 0; kk < 4; kk++)
    #pragma unroll
    for (int j = 0; j < 2; j++) {
      int row = wr * 32 + j * 16 + cl;
      int c0e = kk * 32 + hi8;
      bfh[kk][j] = *(const bfrag*)(Xraw + row * 256 + ((c0e * 2) ^ swzr(row)));
    }
  float hinv[2];
  #pragma unroll
  for (int j = 0; j < 2; j++) hinv[j] = invb[wr * 32 + j * 16 + cl];
  __syncthreads();                        // B-H: Xraw dead -> fbuf may be written

  facc zero = {0.f, 0.f, 0.f, 0.f};
  facc e_acc[2][2];
  e_acc[0][0] = zero; e_acc[0][1] = zero; e_acc[1][0] = zero; e_acc[1][1] = zero;

  for (int dch = 0; dch < 4; dch++) {
    // f-MFMA: D[d][l], wave tile 64d x 32l (A=Ws from LDS, B=Xraw hoisted)
    facc acc[4][2];
    #pragma unroll
    for (int m = 0; m < 4; m++) { acc[m][0] = zero; acc[m][1] = zero; }
    #pragma unroll
    for (int kk = 0; kk < 4; kk++) {
      int c0e = kk * 32 + hi8;
      bfrag am[4];
      #pragma unroll
      for (int m = 0; m < 4; m++) {
        int d = wc * 64 + m * 16 + cl;
        am[m] = *(const bfrag*)(Ws + d * 256 + ((c0e * 2) ^ swzr(d)));
      }
      #pragma unroll
      for (int m = 0; m < 4; m++)
        #pragma unroll
        for (int j = 0; j < 2; j++)
          acc[m][j] = __builtin_amdgcn_mfma_f32_16x16x32_bf16(am[m], bfh[kk][j], acc[m][j], 0, 0, 0);
    }
    // epilogue: f = inv[l]*acc + bias -> fbuf(l,d); quad spans d -> b64 writes
    #pragma unroll
    for (int m = 0; m < 4; m++) {
      int d0 = wc * 64 + m * 16 + r0;
      float4 bq = *(const float4*)(conv_b + dch * 128 + d0);
      #pragma unroll
      for (int j = 0; j < 2; j++) {
        int l = wr * 32 + j * 16 + cl;
        uint2 w;
        w.x = f2bf2(acc[m][j][0] * hinv[j] + bq.x, acc[m][j][1] * hinv[j] + bq.y);
        w.y = f2bf2(acc[m][j][2] * hinv[j] + bq.z, acc[m][j][3] * hinv[j] + bq.w);
        *(uint2*)(fbuf + l * 256 + ((d0 * 2) ^ swzr(l))) = w;
      }
    }
    __syncthreads();                      // B_mid: fbuf visible; Ws reads done
    // ca loads from global (L2-hot; latency hides under dump + stage issue)
    bfrag ca[4][2];
    {
      const unsigned short* cb0 = Cb + (size_t)(er * 32 + cl) * DD + dch * 128 + hi8;
      #pragma unroll
      for (int kk = 0; kk < 4; kk++) {
        ca[kk][0] = *(const bfrag*)(cb0 + kk * 32);
        ca[kk][1] = *(const bfrag*)(cb0 + 16 * DD + kk * 32);
      }
    }
    // issue next Ws stage (lands by B_top; overlaps dump + e-MFMA)
    if (dch < 3) {
      #pragma unroll
      for (int q = 0; q < 4; q++)
        gll16((const char*)Wsw + (dch + 1) * 32768 + (q * 8 + wid) * 1024 + lane * 16,
              Ws + (q * 8 + wid) * 1024);
    }
    // coalesced fT dump (stores overlap e-MFMA)
    {
      int lr = t >> 2;
      #pragma unroll
      for (int p = 0; p < 4; p++) {
        int c16 = (t & 3) + 4 * p;
        bfrag v = *(const bfrag*)(fbuf + lr * 256 + ((c16 * 16) ^ swzr(lr)));
        *(bfrag*)(fT + ((size_t)n * HW + l0 + lr) * DD + dch * 128 + c16 * 8) = v;
      }
    }
    // e-MFMA: e_acc += Cb(64k x 128d) x fbuf(128l x 128d)^T, wave tile 32k x 32l
    #pragma unroll
    for (int kk = 0; kk < 4; kk++) {
      int d0 = kk * 32 + hi8;
      bfrag fb[2];
      #pragma unroll
      for (int j2 = 0; j2 < 2; j2++) {
        int l2 = ec * 32 + j2 * 16 + cl;
        fb[j2] = *(const bfrag*)(fbuf + l2 * 256 + ((d0 * 2) ^ swzr(l2)));
      }
      #pragma unroll
      for (int m2 = 0; m2 < 2; m2++)
        #pragma unroll
        for (int j2 = 0; j2 < 2; j2++)
          e_acc[m2][j2] = __builtin_amdgcn_mfma_f32_16x16x32_bf16(ca[kk][m2], fb[j2], e_acc[m2][j2], 0, 0, 0);
    }
    __syncthreads();                      // B_top: stage drained; fbuf reads done
  }

  // P5: exp -> etile (aliases Ws, dead) + rowsum partials
  {
    int l2base = ec * 32;
    #pragma unroll
    for (int m2 = 0; m2 < 2; m2++) {
      #pragma unroll
      for (int q = 0; q < 4; q++) {
        int k2 = er * 32 + m2 * 16 + r0 + q;
        float vsum = 0.f;
        #pragma unroll
        for (int j2 = 0; j2 < 2; j2++) {
          int l2 = l2base + j2 * 16 + cl;
          float ev = __expf(e_acc[m2][j2][q]);
          *(unsigned short*)(etile + (l2 >> 6) * 8192 + k2 * 128 +
                             (((l2 & 63) * 2) ^ swzr(k2))) = f2bf(ev);
          vsum += ev;
        }
        vsum += __shfl_xor(vsum, 1); vsum += __shfl_xor(vsum, 2);
        vsum += __shfl_xor(vsum, 4); vsum += __shfl_xor(vsum, 8);
        if (cl == 0) ps[k2 * 4 + ec] = vsum;
      }
    }
  }
  __syncthreads();
  // dump 2 e-images (16K contiguous) + psums
  {
    size_t base = ((size_t)n * 64 + lblk * 2) * 8192;
    #pragma unroll
    for (int p = 0; p < 2; p++) {
      uint4 v = *(const uint4*)(etile + (t + p * 512) * 16);
      *(uint4*)((char*)eg + base + (t + p * 512) * 16) = v;
    }
  }
  if (t < 64) {
    float4 v = ((const float4*)ps)[t];
    psums[((size_t)n * 32 + lblk) * 64 + t] = v.x + v.y + v.z + v.w;
  }
}

// ---------- rinv[n,k] = 1 / sum_tiles psums ----------
__global__ __launch_bounds__(256) void k_rinv(const float* __restrict__ psums,
                                              float* __restrict__ rinv) {
  int i = blockIdx.x * 256 + threadIdx.x;       // 1024 total
  int n = i >> 6, k = i & 63;
  float s = 0.f;
  #pragma unroll
  for (int tn = 0; tn < 32; tn++) s += psums[((size_t)n * 32 + tn) * 64 + k];
  rinv[i] = 1.0f / s;
}

// ---------- vlad partials: part[sk,n,k,d] = sum_l e[n,k,l] f[n,l,d] ----------
__global__ __launch_bounds__(256) void k_vlad(const unsigned short* __restrict__ eg,
                                              const unsigned short* __restrict__ fT,
                                              float* __restrict__ part) {
  __shared__ __align__(16) char smem[49152];
  char* As = smem;            // 2 images x [64k x 128B]: k*128 + ((l''*2)^swzr(k))
  char* Bs = smem + 16384;    // [128d][128l]: d*256 + ((l*2)^(((d&7)^((d>>3)&7))<<4))
  int t = threadIdx.x, lane = t & 63, wid = t >> 6;
  int wr = wid >> 1, wc = wid & 1;
  int lin = blockIdx.x;
  int xcd = lin & 7, jj = lin >> 3;
  int grp = xcd * 8 + (jj >> 2);                // 0..63 = (n,sk)
  int dt = jj & 3, n = grp >> 2, sk = grp & 3;
  int dbase = dt * 128;
  facc acc[2][4];
  facc zero = {0.f, 0.f, 0.f, 0.f};
  #pragma unroll
  for (int m = 0; m < 2; m++)
    #pragma unroll
    for (int j = 0; j < 4; j++) acc[m][j] = zero;

  for (int ks = 0; ks < 8; ks++) {
    int l0 = sk * 1024 + ks * 128;
    {   // stage A: two consecutive 8K e-images via gll16
      const char* easrc = (const char*)eg + ((size_t)n * 64 + (l0 >> 6)) * 8192;
      #pragma unroll
      for (int q = 0; q < 4; q++)
        gll16(easrc + (q * 4 + wid) * 1024 + lane * 16, As + (q * 4 + wid) * 1024);
    }
    // stage B transposed (fT rows l -> Bs[d][l])
    #pragma unroll
    for (int q = 0; q < 8; q++) {
      int ch = q * 256 + t;
      int l = ch >> 4, dc = ch & 15;
      bfrag v = *(const bfrag*)(fT + ((size_t)n * HW + l0 + l) * DD + dbase + dc * 8);
      #pragma unroll
      for (int i = 0; i < 8; i++) {
        int d = dc * 8 + i;
        int swz = (((d & 7) ^ ((d >> 3) & 7)) << 4);
        *(unsigned short*)(Bs + d * 256 + ((l * 2) ^ swz)) = (unsigned short)v[i];
      }
    }
    __syncthreads();
    #pragma unroll
    for (int kk = 0; kk < 128; kk += 32) {
      int lk = kk + ((lane >> 4) << 3);
      const char* Ai = As + (kk >> 6) * 8192;
      int ll = lk & 63;
      bfrag af[2], bf[4];
      #pragma unroll
      for (int m = 0; m < 2; m++) {
        int krow = wr * 32 + m * 16 + (lane & 15);
        af[m] = *(const bfrag*)(Ai + krow * 128 + ((ll * 2) ^ swzr(krow)));
      }
      #pragma unroll
      for (int j = 0; j < 4; j++) {
        int d = wc * 64 + j * 16 + (lane & 15);
        int swz = (((d & 7) ^ ((d >> 3) & 7)) << 4);
        bf[j] = *(const bfrag*)(Bs + d * 256 + ((lk * 2) ^ swz));
      }
      #pragma unroll
      for (int m = 0; m < 2; m++)
        #pragma unroll
        for (int j = 0; j < 4; j++)
          acc[m][j] = __builtin_amdgcn_mfma_f32_16x16x32_bf16(af[m], bf[j], acc[m][j], 0, 0, 0);
    }
    __syncthreads();
  }
  int r0 = (lane >> 4) << 2, cl = lane & 15;
  size_t base = ((size_t)(sk * NB + n)) * (KC * DD);
  #pragma unroll
  for (int m = 0; m < 2; m++) {
    int krow = wr * 32 + m * 16 + r0;
    #pragma unroll
    for (int j = 0; j < 4; j++) {
      int d = dbase + wc * 64 + j * 16 + cl;
      #pragma unroll
      for (int q = 0; q < 4; q++)
        part[base + (size_t)(krow + q) * DD + d] = acc[m][j][q];
    }
  }
}

// ---------- reduce split-K partials (4) and normalize by rinv ----------
__global__ __launch_bounds__(256) void k_reduce(const float* __restrict__ part,
                                                const float* __restrict__ rinv,
                                                float* __restrict__ out) {
  int i = blockIdx.x * 256 + threadIdx.x;
  float s = 0.f;
  #pragma unroll
  for (int skk = 0; skk < 4; skk++) s += part[(size_t)skk * (NB * KC * DD) + i];
  out[i] = s * rinv[i >> 9];                    // i>>9 = n*64+k
}

extern "C" void kernel_launch(void* const* d_in, const int* in_sizes, int n_in,
                              void* d_out, int out_size, void* d_ws, size_t ws_size,
                              hipStream_t stream) {
  const float* x         = (const float*)d_in[0];
  const float* conv_w    = (const float*)d_in[1];
  const float* conv_b    = (const float*)d_in[2];
  const float* centroids = (const float*)d_in[3];
  float* out = (float*)d_out;
  char* ws = (char*)d_ws;

  // ws layout (bytes):
  //   Wsw   @ 0          (128 KB)   conv_w bf16, 4x32K pre-swizzled images
  //   Cb    @ 131072     (64 KB)    normalized centroids bf16 (K,D) row-major
  //   fT    @ 196608     (64 MB)    f bf16 (N,L,D)
  //   eg    @ 67305472   (8 MB)     exp(logits) bf16, N*64 x 8K images
  //   psums @ 75694080   (128 KB)   per-tile row sums fp32 (N,32,K)
  //   rinv  @ 75956224   (4 KB)     1/rowsum fp32 (N,K)
  //   part  @ 75960320   (8 MB)     vlad partials fp32 (4,N,K,D)
  unsigned short* Wsw  = (unsigned short*)(ws);
  unsigned short* Cb   = (unsigned short*)(ws + 131072);
  unsigned short* fT   = (unsigned short*)(ws + 196608);
  unsigned short* eg   = (unsigned short*)(ws + 67305472ull);
  float*          psums= (float*)(ws + 75694080ull);
  float*          rinv = (float*)(ws + 75956224ull);
  float*          part = (float*)(ws + 75960320ull);

  k_prep<<<dim3(96), dim3(256), 0, stream>>>(conv_w, centroids, Wsw, Cb);

  // fused xnorm + projection + logits/exp -> fT, e-images, psums
  k_xproj<<<dim3(32, NB), dim3(512), 0, stream>>>(x, Wsw, Cb, conv_b, fT, eg, psums);

  k_rinv<<<dim3(4), dim3(256), 0, stream>>>(psums, rinv);

  // vlad partials: e(K,L) * f(L,D), split-L into 4 chunks of 1024
  k_vlad<<<dim3(256), dim3(256), 0, stream>>>(eg, fT, part);

  k_reduce<<<dim3(NB * KC * DD / 256), dim3(256), 0, stream>>>(part, rinv, out);

  (void)in_sizes; (void)n_in; (void)out_size; (void)ws_size;
}

// Round 15
// 80.327 us; speedup vs baseline: 1.0127x; 1.0127x over previous
//
#include <hip/hip_runtime.h>

#define NB 16     // batch
#define CD 128    // channels
#define HW 4096   // spatial L
#define DD 512    // projected dim
#define KC 64     // clusters

typedef __attribute__((ext_vector_type(8))) short bfrag;           // 8 bf16 (4 VGPR)
typedef __attribute__((ext_vector_type(4))) float facc;            // MFMA acc

__device__ __forceinline__ unsigned short f2bf(float f) {
  union { float f; unsigned u; } v; v.f = f;
  unsigned r = v.u + 0x7fffu + ((v.u >> 16) & 1u);   // RNE
  return (unsigned short)(r >> 16);
}
__device__ __forceinline__ float bf2f(unsigned short h) {
  union { unsigned u; float f; } v; v.u = ((unsigned)h) << 16; return v.f;
}
// packed f32x2 -> bf16x2 (RNE), low16 = lo
__device__ __forceinline__ unsigned f2bf2(float lo, float hi) {
  unsigned r;
  asm("v_cvt_pk_bf16_f32 %0, %1, %2" : "=v"(r) : "v"(lo), "v"(hi));
  return r;
}
// async global->LDS: HW writes lds_base + lane*16; global src carries per-lane offset
__device__ __forceinline__ void gll16(const void* g, void* l) {
  __builtin_amdgcn_global_load_lds(
      (__attribute__((address_space(1))) void*)(uintptr_t)g,
      (__attribute__((address_space(3))) void*)(uintptr_t)l, 16, 0, 0);
}
// row swizzle: spreads row-parallel accesses across 8 16B slots
__device__ __forceinline__ int swzr(int r) { return ((r & 7) ^ ((r >> 3) & 7)) << 4; }

// ---------- prep: pre-swizzled W images + plain normalized centroids ----------
// Wsw: 4 images x [128d x 256B], byte = dch*32768 + d*256 + ((c*2)^swzr(d))
// Cb:  (K,D) row-major bf16, L2-resident (read direct by k_xproj e-MFMA)
__global__ __launch_bounds__(256) void k_prep(const float* __restrict__ conv_w,
                                              const float* __restrict__ centroids,
                                              unsigned short* __restrict__ Wsw,
                                              unsigned short* __restrict__ Cb) {
  int b = blockIdx.x, t = threadIdx.x;
  if (b < KC) {
    const float* row = centroids + (size_t)b * DD;
    float v0 = row[t], v1 = row[t + 256];
    float ss = v0 * v0 + v1 * v1;
    #pragma unroll
    for (int off = 32; off; off >>= 1) ss += __shfl_xor(ss, off);
    __shared__ float red[4];
    if ((t & 63) == 0) red[t >> 6] = ss;
    __syncthreads();
    float tot = red[0] + red[1] + red[2] + red[3];
    float inv = 1.0f / fmaxf(sqrtf(tot), 1e-12f);
    Cb[(size_t)b * DD + t]       = f2bf(v0 * inv);
    Cb[(size_t)b * DD + t + 256] = f2bf(v1 * inv);
  } else {
    int i = (b - KC) * 2048 + t * 8;            // 32 blocks cover 512x128
    const float4* src = (const float4*)(conv_w + i);
    float4 a = src[0], c4 = src[1];
    int d = i >> 7, c0 = i & 127;
    int dch = d >> 7, dl = d & 127;
    uint4 w;
    w.x = f2bf2(a.x, a.y);   w.y = f2bf2(a.z, a.w);
    w.z = f2bf2(c4.x, c4.y); w.w = f2bf2(c4.z, c4.w);
    *(uint4*)((char*)Wsw + dch * 32768 + dl * 256 + ((c0 * 2) ^ swzr(dl))) = w;
  }
}

// ---------- fused xnorm + projection + logits/exp (R14 structure, VGPR cap 128) ----------
// 2 blocks/CU: LDS = Xraw/fbuf 32K | Ws/etile 32K | invb+ps 1.5K.
// Cb read direct from global (L2-hot); bfh hoisted so Xraw dies pre-loop.
__global__ __launch_bounds__(512, 2) void k_xproj(const float* __restrict__ x,
                                                  const unsigned short* __restrict__ Wsw,
                                                  const unsigned short* __restrict__ Cb,
                                                  const float* __restrict__ conv_b,
                                                  unsigned short* __restrict__ fT,
                                                  unsigned short* __restrict__ eg,
                                                  float* __restrict__ psums) {
  __shared__ __align__(16) char smem[67072];
  char* Xraw = smem;                      // 128l x 256B: l*256 + ((c*2)^swzr(l))
  char* fbuf = smem;                      // aliases Xraw (dead after bfh hoist)
  char* Ws   = smem + 32768;              // 128d x 256B (staged image)
  char* etile = smem + 32768;             // aliases Ws (dead after dch3 f-MFMA)
  float* invb = (float*)(smem + 65536);   // [128]
  float* ps   = (float*)(smem + 66048);   // [64][4]
  int n = blockIdx.y, lblk = blockIdx.x, l0 = lblk * 128;
  int t = threadIdx.x, lane = t & 63, wid = t >> 6;

  // prologue: stage Ws(0)
  #pragma unroll
  for (int q = 0; q < 4; q++)
    gll16((const char*)Wsw + (q * 8 + wid) * 1024 + lane * 16, Ws + (q * 8 + wid) * 1024);

  // P1: x fp32 (c-pair rows) -> bf16 -> Xraw (l,c), u32 pair-writes
  #pragma unroll
  for (int j = 0; j < 2; j++) {
    int c0 = ((t >> 4) + 32 * j) * 2;
    const float4* r0p = (const float4*)(x + ((size_t)n * CD + c0) * HW + l0);
    const float4* r1p = (const float4*)(x + ((size_t)n * CD + c0 + 1) * HW + l0);
    #pragma unroll
    for (int jj = 0; jj < 2; jj++) {
      int f4 = (t & 15) + 16 * jj;
      float4 a = r0p[f4], b = r1p[f4];
      int lb = f4 * 4;
      *(unsigned*)(Xraw + (lb + 0) * 256 + ((c0 * 2) ^ swzr(lb + 0))) = f2bf2(a.x, b.x);
      *(unsigned*)(Xraw + (lb + 1) * 256 + ((c0 * 2) ^ swzr(lb + 1))) = f2bf2(a.y, b.y);
      *(unsigned*)(Xraw + (lb + 2) * 256 + ((c0 * 2) ^ swzr(lb + 2))) = f2bf2(a.z, b.z);
      *(unsigned*)(Xraw + (lb + 3) * 256 + ((c0 * 2) ^ swzr(lb + 3))) = f2bf2(a.w, b.w);
    }
  }
  __syncthreads();                        // B-P1: Xraw ready; Ws(0) drained

  // P2: inv[l] from row sums (b128 reads; XOR permutation is sum-invariant)
  {
    int l = t >> 2;
    float ss = 0.f;
    #pragma unroll
    for (int p = 0; p < 4; p++) {
      int s16 = (t & 3) + 4 * p;
      bfrag v = *(const bfrag*)(Xraw + l * 256 + ((s16 * 16) ^ swzr(l)));
      #pragma unroll
      for (int i = 0; i < 8; i++) { float f = bf2f((unsigned short)v[i]); ss += f * f; }
    }
    ss += __shfl_xor(ss, 1); ss += __shfl_xor(ss, 2);
    if ((t & 3) == 0) invb[l] = 1.0f / fmaxf(sqrtf(ss), 1e-12f);
  }
  __syncthreads();                        // B-P2: invb ready

  int wr = wid >> 1, wc = wid & 1;        // f waves: 4(l-grp of 32) x 2(d-grp of 64)
  int er = wid >> 2, ec = wid & 3;        // e waves: 2(k) x 4(l)
  int r0 = (lane >> 4) << 2, cl = lane & 15;
  int hi8 = (lane >> 4) << 3;

  // hoist Xraw B-fragments (dch-invariant, 32 VGPR) + per-l-frag inv
  bfrag bfh[4][2];
  #pragma unroll
  for (int kk = 0; kk < 4; kk++)
    #pragma unroll
    for (int j = 0; j < 2; j++) {
      int row = wr * 32 + j * 16 + cl;
      int c0e = kk * 32 + hi8;
      bfh[kk][j] = *(const bfrag*)(Xraw + row * 256 + ((c0e * 2) ^ swzr(row)));
    }
  float hinv[2];
  #pragma unroll
  for (int j = 0; j < 2; j++) hinv[j] = invb[wr * 32 + j * 16 + cl];
  __syncthreads();                        // B-H: Xraw dead -> fbuf may be written

  facc zero = {0.f, 0.f, 0.f, 0.f};
  facc e_acc[2][2];
  e_acc[0][0] = zero; e_acc[0][1] = zero; e_acc[1][0] = zero; e_acc[1][1] = zero;

  for (int dch = 0; dch < 4; dch++) {
    // f-MFMA: D[d][l], wave tile 64d x 32l (A=Ws from LDS, B=Xraw hoisted)
    facc acc[4][2];
    #pragma unroll
    for (int m = 0; m < 4; m++) { acc[m][0] = zero; acc[m][1] = zero; }
    #pragma unroll
    for (int kk = 0; kk < 4; kk++) {
      int c0e = kk * 32 + hi8;
      bfrag am[4];
      #pragma unroll
      for (int m = 0; m < 4; m++) {
        int d = wc * 64 + m * 16 + cl;
        am[m] = *(const bfrag*)(Ws + d * 256 + ((c0e * 2) ^ swzr(d)));
      }
      #pragma unroll
      for (int m = 0; m < 4; m++)
        #pragma unroll
        for (int j = 0; j < 2; j++)
          acc[m][j] = __builtin_amdgcn_mfma_f32_16x16x32_bf16(am[m], bfh[kk][j], acc[m][j], 0, 0, 0);
    }
    // epilogue: f = inv[l]*acc + bias -> fbuf(l,d); quad spans d -> b64 writes
    #pragma unroll
    for (int m = 0; m < 4; m++) {
      int d0 = wc * 64 + m * 16 + r0;
      float4 bq = *(const float4*)(conv_b + dch * 128 + d0);
      #pragma unroll
      for (int j = 0; j < 2; j++) {
        int l = wr * 32 + j * 16 + cl;
        uint2 w;
        w.x = f2bf2(acc[m][j][0] * hinv[j] + bq.x, acc[m][j][1] * hinv[j] + bq.y);
        w.y = f2bf2(acc[m][j][2] * hinv[j] + bq.z, acc[m][j][3] * hinv[j] + bq.w);
        *(uint2*)(fbuf + l * 256 + ((d0 * 2) ^ swzr(l))) = w;
      }
    }
    __syncthreads();                      // B_mid: fbuf visible; Ws reads done
    // ca loads from global (L2-hot; latency hides under dump + stage issue)
    bfrag ca[4][2];
    {
      const unsigned short* cb0 = Cb + (size_t)(er * 32 + cl) * DD + dch * 128 + hi8;
      #pragma unroll
      for (int kk = 0; kk < 4; kk++) {
        ca[kk][0] = *(const bfrag*)(cb0 + kk * 32);
        ca[kk][1] = *(const bfrag*)(cb0 + 16 * DD + kk * 32);
      }
    }
    // issue next Ws stage (lands by B_top; overlaps dump + e-MFMA)
    if (dch < 3) {
      #pragma unroll
      for (int q = 0; q < 4; q++)
        gll16((const char*)Wsw + (dch + 1) * 32768 + (q * 8 + wid) * 1024 + lane * 16,
              Ws + (q * 8 + wid) * 1024);
    }
    // coalesced fT dump (stores overlap e-MFMA)
    {
      int lr = t >> 2;
      #pragma unroll
      for (int p = 0; p < 4; p++) {
        int c16 = (t & 3) + 4 * p;
        bfrag v = *(const bfrag*)(fbuf + lr * 256 + ((c16 * 16) ^ swzr(lr)));
        *(bfrag*)(fT + ((size_t)n * HW + l0 + lr) * DD + dch * 128 + c16 * 8) = v;
      }
    }
    // e-MFMA: e_acc += Cb(64k x 128d) x fbuf(128l x 128d)^T, wave tile 32k x 32l
    #pragma unroll
    for (int kk = 0; kk < 4; kk++) {
      int d0 = kk * 32 + hi8;
      bfrag fb[2];
      #pragma unroll
      for (int j2 = 0; j2 < 2; j2++) {
        int l2 = ec * 32 + j2 * 16 + cl;
        fb[j2] = *(const bfrag*)(fbuf + l2 * 256 + ((d0 * 2) ^ swzr(l2)));
      }
      #pragma unroll
      for (int m2 = 0; m2 < 2; m2++)
        #pragma unroll
        for (int j2 = 0; j2 < 2; j2++)
          e_acc[m2][j2] = __builtin_amdgcn_mfma_f32_16x16x32_bf16(ca[kk][m2], fb[j2], e_acc[m2][j2], 0, 0, 0);
    }
    __syncthreads();                      // B_top: stage drained; fbuf reads done
  }

  // P5: exp -> etile (aliases Ws, dead) + rowsum partials
  {
    int l2base = ec * 32;
    #pragma unroll
    for (int m2 = 0; m2 < 2; m2++) {
      #pragma unroll
      for (int q = 0; q < 4; q++) {
        int k2 = er * 32 + m2 * 16 + r0 + q;
        float vsum = 0.f;
        #pragma unroll
        for (int j2 = 0; j2 < 2; j2++) {
          int l2 = l2base + j2 * 16 + cl;
          float ev = __expf(e_acc[m2][j2][q]);
          *(unsigned short*)(etile + (l2 >> 6) * 8192 + k2 * 128 +
                             (((l2 & 63) * 2) ^ swzr(k2))) = f2bf(ev);
          vsum += ev;
        }
        vsum += __shfl_xor(vsum, 1); vsum += __shfl_xor(vsum, 2);
        vsum += __shfl_xor(vsum, 4); vsum += __shfl_xor(vsum, 8);
        if (cl == 0) ps[k2 * 4 + ec] = vsum;
      }
    }
  }
  __syncthreads();
  // dump 2 e-images (16K contiguous) + psums
  {
    size_t base = ((size_t)n * 64 + lblk * 2) * 8192;
    #pragma unroll
    for (int p = 0; p < 2; p++) {
      uint4 v = *(const uint4*)(etile + (t + p * 512) * 16);
      *(uint4*)((char*)eg + base + (t + p * 512) * 16) = v;
    }
  }
  if (t < 64) {
    float4 v = ((const float4*)ps)[t];
    psums[((size_t)n * 32 + lblk) * 64 + t] = v.x + v.y + v.z + v.w;
  }
}

// ---------- rinv[n,k] = 1 / sum_tiles psums ----------
__global__ __launch_bounds__(256) void k_rinv(const float* __restrict__ psums,
                                              float* __restrict__ rinv) {
  int i = blockIdx.x * 256 + threadIdx.x;       // 1024 total
  int n = i >> 6, k = i & 63;
  float s = 0.f;
  #pragma unroll
  for (int tn = 0; tn < 32; tn++) s += psums[((size_t)n * 32 + tn) * 64 + k];
  rinv[i] = 1.0f / s;
}

// ---------- vlad partials: part[sk,n,k,d] = sum_l e[n,k,l] f[n,l,d] ----------
__global__ __launch_bounds__(256) void k_vlad(const unsigned short* __restrict__ eg,
                                              const unsigned short* __restrict__ fT,
                                              float* __restrict__ part) {
  __shared__ __align__(16) char smem[49152];
  char* As = smem;            // 2 images x [64k x 128B]: k*128 + ((l''*2)^swzr(k))
  char* Bs = smem + 16384;    // [128d][128l]: d*256 + ((l*2)^(((d&7)^((d>>3)&7))<<4))
  int t = threadIdx.x, lane = t & 63, wid = t >> 6;
  int wr = wid >> 1, wc = wid & 1;
  int lin = blockIdx.x;
  int xcd = lin & 7, jj = lin >> 3;
  int grp = xcd * 8 + (jj >> 2);                // 0..63 = (n,sk)
  int dt = jj & 3, n = grp >> 2, sk = grp & 3;
  int dbase = dt * 128;
  facc acc[2][4];
  facc zero = {0.f, 0.f, 0.f, 0.f};
  #pragma unroll
  for (int m = 0; m < 2; m++)
    #pragma unroll
    for (int j = 0; j < 4; j++) acc[m][j] = zero;

  for (int ks = 0; ks < 8; ks++) {
    int l0 = sk * 1024 + ks * 128;
    {   // stage A: two consecutive 8K e-images via gll16
      const char* easrc = (const char*)eg + ((size_t)n * 64 + (l0 >> 6)) * 8192;
      #pragma unroll
      for (int q = 0; q < 4; q++)
        gll16(easrc + (q * 4 + wid) * 1024 + lane * 16, As + (q * 4 + wid) * 1024);
    }
    // stage B transposed (fT rows l -> Bs[d][l])
    #pragma unroll
    for (int q = 0; q < 8; q++) {
      int ch = q * 256 + t;
      int l = ch >> 4, dc = ch & 15;
      bfrag v = *(const bfrag*)(fT + ((size_t)n * HW + l0 + l) * DD + dbase + dc * 8);
      #pragma unroll
      for (int i = 0; i < 8; i++) {
        int d = dc * 8 + i;
        int swz = (((d & 7) ^ ((d >> 3) & 7)) << 4);
        *(unsigned short*)(Bs + d * 256 + ((l * 2) ^ swz)) = (unsigned short)v[i];
      }
    }
    __syncthreads();
    #pragma unroll
    for (int kk = 0; kk < 128; kk += 32) {
      int lk = kk + ((lane >> 4) << 3);
      const char* Ai = As + (kk >> 6) * 8192;
      int ll = lk & 63;
      bfrag af[2], bf[4];
      #pragma unroll
      for (int m = 0; m < 2; m++) {
        int krow = wr * 32 + m * 16 + (lane & 15);
        af[m] = *(const bfrag*)(Ai + krow * 128 + ((ll * 2) ^ swzr(krow)));
      }
      #pragma unroll
      for (int j = 0; j < 4; j++) {
        int d = wc * 64 + j * 16 + (lane & 15);
        int swz = (((d & 7) ^ ((d >> 3) & 7)) << 4);
        bf[j] = *(const bfrag*)(Bs + d * 256 + ((lk * 2) ^ swz));
      }
      #pragma unroll
      for (int m = 0; m < 2; m++)
        #pragma unroll
        for (int j = 0; j < 4; j++)
          acc[m][j] = __builtin_amdgcn_mfma_f32_16x16x32_bf16(af[m], bf[j], acc[m][j], 0, 0, 0);
    }
    __syncthreads();
  }
  int r0 = (lane >> 4) << 2, cl = lane & 15;
  size_t base = ((size_t)(sk * NB + n)) * (KC * DD);
  #pragma unroll
  for (int m = 0; m < 2; m++) {
    int krow = wr * 32 + m * 16 + r0;
    #pragma unroll
    for (int j = 0; j < 4; j++) {
      int d = dbase + wc * 64 + j * 16 + cl;
      #pragma unroll
      for (int q = 0; q < 4; q++)
        part[base + (size_t)(krow + q) * DD + d] = acc[m][j][q];
    }
  }
}

// ---------- reduce split-K partials (4) and normalize by rinv ----------
__global__ __launch_bounds__(256) void k_reduce(const float* __restrict__ part,
                                                const float* __restrict__ rinv,
                                                float* __restrict__ out) {
  int i = blockIdx.x * 256 + threadIdx.x;
  float s = 0.f;
  #pragma unroll
  for (int skk = 0; skk < 4; skk++) s += part[(size_t)skk * (NB * KC * DD) + i];
  out[i] = s * rinv[i >> 9];                    // i>>9 = n*64+k
}

extern "C" void kernel_launch(void* const* d_in, const int* in_sizes, int n_in,
                              void* d_out, int out_size, void* d_ws, size_t ws_size,
                              hipStream_t stream) {
  const float* x         = (const float*)d_in[0];
  const float* conv_w    = (const float*)d_in[1];
  const float* conv_b    = (const float*)d_in[2];
  const float* centroids = (const float*)d_in[3];
  float* out = (float*)d_out;
  char* ws = (char*)d_ws;

  // ws layout (bytes):
  //   Wsw   @ 0          (128 KB)   conv_w bf16, 4x32K pre-swizzled images
  //   Cb    @ 131072     (64 KB)    normalized centroids bf16 (K,D) row-major
  //   fT    @ 196608     (64 MB)    f bf16 (N,L,D)
  //   eg    @ 67305472   (8 MB)     exp(logits) bf16, N*64 x 8K images
  //   psums @ 75694080   (128 KB)   per-tile row sums fp32 (N,32,K)
  //   rinv  @ 75956224   (4 KB)     1/rowsum fp32 (N,K)
  //   part  @ 75960320   (8 MB)     vlad partials fp32 (4,N,K,D)
  unsigned short* Wsw  = (unsigned short*)(ws);
  unsigned short* Cb   = (unsigned short*)(ws + 131072);
  unsigned short* fT   = (unsigned short*)(ws + 196608);
  unsigned short* eg   = (unsigned short*)(ws + 67305472ull);
  float*          psums= (float*)(ws + 75694080ull);
  float*          rinv = (float*)(ws + 75956224ull);
  float*          part = (float*)(ws + 75960320ull);

  k_prep<<<dim3(96), dim3(256), 0, stream>>>(conv_w, centroids, Wsw, Cb);

  // fused xnorm + projection + logits/exp -> fT, e-images, psums
  k_xproj<<<dim3(32, NB), dim3(512), 0, stream>>>(x, Wsw, Cb, conv_b, fT, eg, psums);

  k_rinv<<<dim3(4), dim3(256), 0, stream>>>(psums, rinv);

  // vlad partials: e(K,L) * f(L,D), split-L into 4 chunks of 1024
  k_vlad<<<dim3(256), dim3(256), 0, stream>>>(eg, fT, part);

  k_reduce<<<dim3(NB * KC * DD / 256), dim3(256), 0, stream>>>(part, rinv, out);

  (void)in_sizes; (void)n_in; (void)out_size; (void)ws_size;
}

// Round 16
// 67.320 us; speedup vs baseline: 1.2083x; 1.1932x over previous
//
#include <hip/hip_runtime.h>

#define NB 16     // batch
#define CD 128    // channels
#define HW 4096   // spatial L
#define DD 512    // projected dim
#define KC 64     // clusters

typedef __attribute__((ext_vector_type(8))) short bfrag;           // 8 bf16 (4 VGPR)
typedef __attribute__((ext_vector_type(4))) float facc;            // MFMA acc

__device__ __forceinline__ unsigned short f2bf(float f) {
  union { float f; unsigned u; } v; v.f = f;
  unsigned r = v.u + 0x7fffu + ((v.u >> 16) & 1u);   // RNE
  return (unsigned short)(r >> 16);
}
__device__ __forceinline__ float bf2f(unsigned short h) {
  union { unsigned u; float f; } v; v.u = ((unsigned)h) << 16; return v.f;
}
// packed f32x2 -> bf16x2 (RNE), low16 = lo
__device__ __forceinline__ unsigned f2bf2(float lo, float hi) {
  unsigned r;
  asm("v_cvt_pk_bf16_f32 %0, %1, %2" : "=v"(r) : "v"(lo), "v"(hi));
  return r;
}
// async global->LDS: HW writes lds_base + lane*16; global src carries per-lane offset
__device__ __forceinline__ void gll16(const void* g, void* l) {
  __builtin_amdgcn_global_load_lds(
      (__attribute__((address_space(1))) void*)(uintptr_t)g,
      (__attribute__((address_space(3))) void*)(uintptr_t)l, 16, 0, 0);
}
// row swizzle: spreads row-parallel accesses across 8 16B slots
__device__ __forceinline__ int swzr(int r) { return ((r & 7) ^ ((r >> 3) & 7)) << 4; }

// ---------- prep: pre-swizzled W / normalized-centroid LDS images ----------
// Wsw:  4 images x [128d x 256B], byte = dch*32768 + d*256 + ((c*2)^swzr(d))
// Cbsw: 4 images x [64k x 256B],  byte = dch*16384 + k*256 + ((dl*2)^swzr(k))
__global__ __launch_bounds__(256) void k_prep(const float* __restrict__ conv_w,
                                              const float* __restrict__ centroids,
                                              unsigned short* __restrict__ Wsw,
                                              unsigned short* __restrict__ Cbsw) {
  int b = blockIdx.x, t = threadIdx.x;
  if (b < KC) {
    const float* row = centroids + (size_t)b * DD;
    float v0 = row[t], v1 = row[t + 256];
    float ss = v0 * v0 + v1 * v1;
    #pragma unroll
    for (int off = 32; off; off >>= 1) ss += __shfl_xor(ss, off);
    __shared__ float red[4];
    if ((t & 63) == 0) red[t >> 6] = ss;
    __syncthreads();
    float tot = red[0] + red[1] + red[2] + red[3];
    float inv = 1.0f / fmaxf(sqrtf(tot), 1e-12f);
    int d0 = t, d1 = t + 256;
    *(unsigned short*)((char*)Cbsw + (d0 >> 7) * 16384 + b * 256 +
                       (((d0 & 127) * 2) ^ swzr(b))) = f2bf(v0 * inv);
    *(unsigned short*)((char*)Cbsw + (d1 >> 7) * 16384 + b * 256 +
                       (((d1 & 127) * 2) ^ swzr(b))) = f2bf(v1 * inv);
  } else {
    int i = (b - KC) * 2048 + t * 8;            // 32 blocks cover 512x128
    const float4* src = (const float4*)(conv_w + i);
    float4 a = src[0], c4 = src[1];
    int d = i >> 7, c0 = i & 127;
    int dch = d >> 7, dl = d & 127;
    uint4 w;
    w.x = f2bf2(a.x, a.y);   w.y = f2bf2(a.z, a.w);
    w.z = f2bf2(c4.x, c4.y); w.w = f2bf2(c4.z, c4.w);
    *(uint4*)((char*)Wsw + dch * 32768 + dl * 256 + ((c0 * 2) ^ swzr(dl))) = w;
  }
}

// ---------- fused xnorm + projection + logits/exp (R13 arithmetic, 80KB LDS) ----------
// LDS (81920 B, 2 blocks/CU exactly):
//   [0,32K)   Xraw / fbuf  (fbuf aliases Xraw after bfh hoist)
//   [32K,64K) Ws / etile   (etile aliases Ws after dch3 f-MFMA)
//   [64K,80K) Cbs (single buffer, staged at iter top) / invb+ps (disjoint live ranges)
__global__ __launch_bounds__(512, 2) void k_xproj(const float* __restrict__ x,
                                                  const unsigned short* __restrict__ Wsw,
                                                  const unsigned short* __restrict__ Cbsw,
                                                  const float* __restrict__ conv_b,
                                                  unsigned short* __restrict__ fT,
                                                  unsigned short* __restrict__ eg,
                                                  float* __restrict__ psums) {
  __shared__ __align__(16) char smem[81920];
  char* Xraw = smem;                      // 128l x 256B: l*256 + ((c*2)^swzr(l))
  char* fbuf = smem;                      // aliases Xraw (dead after bfh hoist)
  char* Ws   = smem + 32768;              // 128d x 256B (staged image)
  char* etile = smem + 32768;             // 2 img x [64k x 128B], aliases Ws
  char* Cbs  = smem + 65536;              // 64k x 256B (staged image)
  float* invb = (float*)(smem + 65536);   // [128] — dies before first Cbs stage
  float* ps   = (float*)(smem + 66560);   // [64][4] — used after Cbs dead
  int n = blockIdx.y, lblk = blockIdx.x, l0 = lblk * 128;
  int t = threadIdx.x, lane = t & 63, wid = t >> 6;

  // prologue: stage Ws(0) only (drained at B-P1)
  #pragma unroll
  for (int q = 0; q < 4; q++)
    gll16((const char*)Wsw + (q * 8 + wid) * 1024 + lane * 16, Ws + (q * 8 + wid) * 1024);

  // P1: x fp32 (c-pair rows) -> bf16 -> Xraw (l,c), u32 pair-writes
  #pragma unroll
  for (int j = 0; j < 2; j++) {
    int c0 = ((t >> 4) + 32 * j) * 2;
    const float4* r0p = (const float4*)(x + ((size_t)n * CD + c0) * HW + l0);
    const float4* r1p = (const float4*)(x + ((size_t)n * CD + c0 + 1) * HW + l0);
    #pragma unroll
    for (int jj = 0; jj < 2; jj++) {
      int f4 = (t & 15) + 16 * jj;
      float4 a = r0p[f4], b = r1p[f4];
      int lb = f4 * 4;
      *(unsigned*)(Xraw + (lb + 0) * 256 + ((c0 * 2) ^ swzr(lb + 0))) = f2bf2(a.x, b.x);
      *(unsigned*)(Xraw + (lb + 1) * 256 + ((c0 * 2) ^ swzr(lb + 1))) = f2bf2(a.y, b.y);
      *(unsigned*)(Xraw + (lb + 2) * 256 + ((c0 * 2) ^ swzr(lb + 2))) = f2bf2(a.z, b.z);
      *(unsigned*)(Xraw + (lb + 3) * 256 + ((c0 * 2) ^ swzr(lb + 3))) = f2bf2(a.w, b.w);
    }
  }
  __syncthreads();                        // B-P1: Xraw ready; Ws(0) drained

  // P2: inv[l] from row sums (b128 reads; XOR permutation is sum-invariant)
  {
    int l = t >> 2;
    float ss = 0.f;
    #pragma unroll
    for (int p = 0; p < 4; p++) {
      int s16 = (t & 3) + 4 * p;
      bfrag v = *(const bfrag*)(Xraw + l * 256 + ((s16 * 16) ^ swzr(l)));
      #pragma unroll
      for (int i = 0; i < 8; i++) { float f = bf2f((unsigned short)v[i]); ss += f * f; }
    }
    ss += __shfl_xor(ss, 1); ss += __shfl_xor(ss, 2);
    if ((t & 3) == 0) invb[l] = 1.0f / fmaxf(sqrtf(ss), 1e-12f);
  }
  __syncthreads();                        // B-P2: invb ready

  int wr = wid >> 1, wc = wid & 1;        // f waves: 4(l-grp of 32) x 2(d-grp of 64)
  int er = wid >> 2, ec = wid & 3;        // e waves: 2(k) x 4(l)
  int r0 = (lane >> 4) << 2, cl = lane & 15;
  int hi8 = (lane >> 4) << 3;

  // hoist Xraw B-fragments (dch-invariant, 32 VGPR) + per-l-frag inv
  bfrag bfh[4][2];
  #pragma unroll
  for (int kk = 0; kk < 4; kk++)
    #pragma unroll
    for (int j = 0; j < 2; j++) {
      int row = wr * 32 + j * 16 + cl;
      int c0e = kk * 32 + hi8;
      bfh[kk][j] = *(const bfrag*)(Xraw + row * 256 + ((c0e * 2) ^ swzr(row)));
    }
  float hinv[2];
  #pragma unroll
  for (int j = 0; j < 2; j++) hinv[j] = invb[wr * 32 + j * 16 + cl];
  __syncthreads();                        // B-H: Xraw/invb dead -> fbuf/Cbs usable

  facc zero = {0.f, 0.f, 0.f, 0.f};
  facc e_acc[2][2];
  e_acc[0][0] = zero; e_acc[0][1] = zero; e_acc[1][0] = zero; e_acc[1][1] = zero;

  for (int dch = 0; dch < 4; dch++) {
    // iter top: stage Cbs(dch) — drains at B_mid, consumed by e-MFMA after B_mid.
    // Previous iter's Cbs reads finished at B_top, so overwrite is safe.
    #pragma unroll
    for (int q = 0; q < 2; q++)
      gll16((const char*)Cbsw + dch * 16384 + (q * 8 + wid) * 1024 + lane * 16,
            Cbs + (q * 8 + wid) * 1024);
    // f-MFMA: D[d][l], wave tile 64d x 32l (A=Ws from LDS, B=Xraw hoisted)
    facc acc[4][2];
    #pragma unroll
    for (int m = 0; m < 4; m++) { acc[m][0] = zero; acc[m][1] = zero; }
    #pragma unroll
    for (int kk = 0; kk < 4; kk++) {
      int c0e = kk * 32 + hi8;
      bfrag am[4];
      #pragma unroll
      for (int m = 0; m < 4; m++) {
        int d = wc * 64 + m * 16 + cl;
        am[m] = *(const bfrag*)(Ws + d * 256 + ((c0e * 2) ^ swzr(d)));
      }
      #pragma unroll
      for (int m = 0; m < 4; m++)
        #pragma unroll
        for (int j = 0; j < 2; j++)
          acc[m][j] = __builtin_amdgcn_mfma_f32_16x16x32_bf16(am[m], bfh[kk][j], acc[m][j], 0, 0, 0);
    }
    // epilogue: f = inv[l]*acc + bias -> fbuf(l,d); quad spans d -> b64 writes
    #pragma unroll
    for (int m = 0; m < 4; m++) {
      int d0 = wc * 64 + m * 16 + r0;
      float4 bq = *(const float4*)(conv_b + dch * 128 + d0);
      #pragma unroll
      for (int j = 0; j < 2; j++) {
        int l = wr * 32 + j * 16 + cl;
        uint2 w;
        w.x = f2bf2(acc[m][j][0] * hinv[j] + bq.x, acc[m][j][1] * hinv[j] + bq.y);
        w.y = f2bf2(acc[m][j][2] * hinv[j] + bq.z, acc[m][j][3] * hinv[j] + bq.w);
        *(uint2*)(fbuf + l * 256 + ((d0 * 2) ^ swzr(l))) = w;
      }
    }
    __syncthreads();                      // B_mid: fbuf + Cbs(dch) visible; Ws reads done
    // issue next Ws stage (lands by B_top; overlaps dump + e-MFMA)
    if (dch < 3) {
      #pragma unroll
      for (int q = 0; q < 4; q++)
        gll16((const char*)Wsw + (dch + 1) * 32768 + (q * 8 + wid) * 1024 + lane * 16,
              Ws + (q * 8 + wid) * 1024);
    }
    // coalesced fT dump (stores overlap e-MFMA)
    {
      int lr = t >> 2;
      #pragma unroll
      for (int p = 0; p < 4; p++) {
        int c16 = (t & 3) + 4 * p;
        bfrag v = *(const bfrag*)(fbuf + lr * 256 + ((c16 * 16) ^ swzr(lr)));
        *(bfrag*)(fT + ((size_t)n * HW + l0 + lr) * DD + dch * 128 + c16 * 8) = v;
      }
    }
    // e-MFMA: e_acc += Cbs(64k x 128d) x fbuf(128l x 128d)^T, wave tile 32k x 32l
    #pragma unroll
    for (int kk = 0; kk < 4; kk++) {
      int d0 = kk * 32 + hi8;
      bfrag ca[2], fb[2];
      #pragma unroll
      for (int m2 = 0; m2 < 2; m2++) {
        int k2 = er * 32 + m2 * 16 + cl;
        ca[m2] = *(const bfrag*)(Cbs + k2 * 256 + ((d0 * 2) ^ swzr(k2)));
      }
      #pragma unroll
      for (int j2 = 0; j2 < 2; j2++) {
        int l2 = ec * 32 + j2 * 16 + cl;
        fb[j2] = *(const bfrag*)(fbuf + l2 * 256 + ((d0 * 2) ^ swzr(l2)));
      }
      #pragma unroll
      for (int m2 = 0; m2 < 2; m2++)
        #pragma unroll
        for (int j2 = 0; j2 < 2; j2++)
          e_acc[m2][j2] = __builtin_amdgcn_mfma_f32_16x16x32_bf16(ca[m2], fb[j2], e_acc[m2][j2], 0, 0, 0);
    }
    __syncthreads();                      // B_top: Ws stage drained; fbuf/Cbs reads done
  }

  // P5: exp -> etile (aliases Ws, dead) + rowsum partials (ps aliases Cbs, dead)
  {
    int l2base = ec * 32;
    #pragma unroll
    for (int m2 = 0; m2 < 2; m2++) {
      #pragma unroll
      for (int q = 0; q < 4; q++) {
        int k2 = er * 32 + m2 * 16 + r0 + q;
        float vsum = 0.f;
        #pragma unroll
        for (int j2 = 0; j2 < 2; j2++) {
          int l2 = l2base + j2 * 16 + cl;
          float ev = __expf(e_acc[m2][j2][q]);
          *(unsigned short*)(etile + (l2 >> 6) * 8192 + k2 * 128 +
                             (((l2 & 63) * 2) ^ swzr(k2))) = f2bf(ev);
          vsum += ev;
        }
        vsum += __shfl_xor(vsum, 1); vsum += __shfl_xor(vsum, 2);
        vsum += __shfl_xor(vsum, 4); vsum += __shfl_xor(vsum, 8);
        if (cl == 0) ps[k2 * 4 + ec] = vsum;
      }
    }
  }
  __syncthreads();
  // dump 2 e-images (16K contiguous) + psums
  {
    size_t base = ((size_t)n * 64 + lblk * 2) * 8192;
    #pragma unroll
    for (int p = 0; p < 2; p++) {
      uint4 v = *(const uint4*)(etile + (t + p * 512) * 16);
      *(uint4*)((char*)eg + base + (t + p * 512) * 16) = v;
    }
  }
  if (t < 64) {
    float4 v = ((const float4*)ps)[t];
    psums[((size_t)n * 32 + lblk) * 64 + t] = v.x + v.y + v.z + v.w;
  }
}

// ---------- vlad partials: part[sk,n,k,d] = sum_l e[n,k,l] f[n,l,d] ----------
__global__ __launch_bounds__(256) void k_vlad(const unsigned short* __restrict__ eg,
                                              const unsigned short* __restrict__ fT,
                                              float* __restrict__ part) {
  __shared__ __align__(16) char smem[49152];
  char* As = smem;            // 2 images x [64k x 128B]: k*128 + ((l''*2)^swzr(k))
  char* Bs = smem + 16384;    // [128d][128l]: d*256 + ((l*2)^(((d&7)^((d>>3)&7))<<4))
  int t = threadIdx.x, lane = t & 63, wid = t >> 6;
  int wr = wid >> 1, wc = wid & 1;
  int lin = blockIdx.x;
  int xcd = lin & 7, jj = lin >> 3;
  int grp = xcd * 8 + (jj >> 2);                // 0..63 = (n,sk)
  int dt = jj & 3, n = grp >> 2, sk = grp & 3;
  int dbase = dt * 128;
  facc acc[2][4];
  facc zero = {0.f, 0.f, 0.f, 0.f};
  #pragma unroll
  for (int m = 0; m < 2; m++)
    #pragma unroll
    for (int j = 0; j < 4; j++) acc[m][j] = zero;

  for (int ks = 0; ks < 8; ks++) {
    int l0 = sk * 1024 + ks * 128;
    {   // stage A: two consecutive 8K e-images via gll16
      const char* easrc = (const char*)eg + ((size_t)n * 64 + (l0 >> 6)) * 8192;
      #pragma unroll
      for (int q = 0; q < 4; q++)
        gll16(easrc + (q * 4 + wid) * 1024 + lane * 16, As + (q * 4 + wid) * 1024);
    }
    // stage B transposed (fT rows l -> Bs[d][l])
    #pragma unroll
    for (int q = 0; q < 8; q++) {
      int ch = q * 256 + t;
      int l = ch >> 4, dc = ch & 15;
      bfrag v = *(const bfrag*)(fT + ((size_t)n * HW + l0 + l) * DD + dbase + dc * 8);
      #pragma unroll
      for (int i = 0; i < 8; i++) {
        int d = dc * 8 + i;
        int swz = (((d & 7) ^ ((d >> 3) & 7)) << 4);
        *(unsigned short*)(Bs + d * 256 + ((l * 2) ^ swz)) = (unsigned short)v[i];
      }
    }
    __syncthreads();
    #pragma unroll
    for (int kk = 0; kk < 128; kk += 32) {
      int lk = kk + ((lane >> 4) << 3);
      const char* Ai = As + (kk >> 6) * 8192;
      int ll = lk & 63;
      bfrag af[2], bf[4];
      #pragma unroll
      for (int m = 0; m < 2; m++) {
        int krow = wr * 32 + m * 16 + (lane & 15);
        af[m] = *(const bfrag*)(Ai + krow * 128 + ((ll * 2) ^ swzr(krow)));
      }
      #pragma unroll
      for (int j = 0; j < 4; j++) {
        int d = wc * 64 + j * 16 + (lane & 15);
        int swz = (((d & 7) ^ ((d >> 3) & 7)) << 4);
        bf[j] = *(const bfrag*)(Bs + d * 256 + ((lk * 2) ^ swz));
      }
      #pragma unroll
      for (int m = 0; m < 2; m++)
        #pragma unroll
        for (int j = 0; j < 4; j++)
          acc[m][j] = __builtin_amdgcn_mfma_f32_16x16x32_bf16(af[m], bf[j], acc[m][j], 0, 0, 0);
    }
    __syncthreads();
  }
  int r0 = (lane >> 4) << 2, cl = lane & 15;
  size_t base = ((size_t)(sk * NB + n)) * (KC * DD);
  #pragma unroll
  for (int m = 0; m < 2; m++) {
    int krow = wr * 32 + m * 16 + r0;
    #pragma unroll
    for (int j = 0; j < 4; j++) {
      int d = dbase + wc * 64 + j * 16 + cl;
      #pragma unroll
      for (int q = 0; q < 4; q++)
        part[base + (size_t)(krow + q) * DD + d] = acc[m][j][q];
    }
  }
}

// ---------- reduce split-K partials (4), compute rinv inline, normalize ----------
__global__ __launch_bounds__(256) void k_reduce(const float* __restrict__ part,
                                                const float* __restrict__ psums,
                                                float* __restrict__ out) {
  int b = blockIdx.x, t = threadIdx.x;
  int nk = b >> 1;                              // constant per block (256 i's span half a 512-slice)
  int n = nk >> 6, k = nk & 63;
  __shared__ float rsh;
  if (t < 32) {
    float s = psums[((size_t)n * 32 + t) * 64 + k];
    #pragma unroll
    for (int off = 16; off; off >>= 1) s += __shfl_xor(s, off, 32);
    if (t == 0) rsh = 1.0f / s;
  }
  __syncthreads();
  float rinv = rsh;
  int i = b * 256 + t;
  float s = 0.f;
  #pragma unroll
  for (int skk = 0; skk < 4; skk++) s += part[(size_t)skk * (NB * KC * DD) + i];
  out[i] = s * rinv;
}

extern "C" void kernel_launch(void* const* d_in, const int* in_sizes, int n_in,
                              void* d_out, int out_size, void* d_ws, size_t ws_size,
                              hipStream_t stream) {
  const float* x         = (const float*)d_in[0];
  const float* conv_w    = (const float*)d_in[1];
  const float* conv_b    = (const float*)d_in[2];
  const float* centroids = (const float*)d_in[3];
  float* out = (float*)d_out;
  char* ws = (char*)d_ws;

  // ws layout (bytes):
  //   Wsw   @ 0          (128 KB)   conv_w bf16, 4x32K pre-swizzled images
  //   Cbsw  @ 131072     (64 KB)    normalized centroids bf16, 4x16K images
  //   fT    @ 196608     (64 MB)    f bf16 (N,L,D)
  //   eg    @ 67305472   (8 MB)     exp(logits) bf16, N*64 x 8K images
  //   psums @ 75694080   (128 KB)   per-tile row sums fp32 (N,32,K)
  //   part  @ 75960320   (8 MB)     vlad partials fp32 (4,N,K,D)
  unsigned short* Wsw  = (unsigned short*)(ws);
  unsigned short* Cbsw = (unsigned short*)(ws + 131072);
  unsigned short* fT   = (unsigned short*)(ws + 196608);
  unsigned short* eg   = (unsigned short*)(ws + 67305472ull);
  float*          psums= (float*)(ws + 75694080ull);
  float*          part = (float*)(ws + 75960320ull);

  k_prep<<<dim3(96), dim3(256), 0, stream>>>(conv_w, centroids, Wsw, Cbsw);

  // fused xnorm + projection + logits/exp -> fT, e-images, psums
  k_xproj<<<dim3(32, NB), dim3(512), 0, stream>>>(x, Wsw, Cbsw, conv_b, fT, eg, psums);

  // vlad partials: e(K,L) * f(L,D), split-L into 4 chunks of 1024
  k_vlad<<<dim3(256), dim3(256), 0, stream>>>(eg, fT, part);

  k_reduce<<<dim3(NB * KC * DD / 256), dim3(256), 0, stream>>>(part, psums, out);

  (void)in_sizes; (void)n_in; (void)out_size; (void)ws_size;
}